// Round 19
// baseline (338.756 us; speedup 1.0000x reference)
//
#include <hip/hip_runtime.h>
#include <hip/hip_bf16.h>
#include <cstdint>
#include <cstddef>

// Problem constants (B=1)
#define EN 400000   // edges
#define NN 25000    // nodes
// D=128, H=4, DK=DV=32

typedef __attribute__((ext_vector_type(8))) short bf16x8;
typedef __attribute__((ext_vector_type(4))) float f32x4;
typedef __attribute__((ext_vector_type(8))) _Float16 f16x8;

__device__ __forceinline__ short f2bf(float f) {
    unsigned int u = __float_as_uint(f);
    u = (u + 0x7fffu + ((u >> 16) & 1u)) >> 16;   // RNE
    return (short)u;
}
__device__ __forceinline__ float bf2f(short s) {
    return __uint_as_float(((unsigned int)(unsigned short)s) << 16);
}

// Identity ds_bpermute: result is DS-defined, so the compiler cannot rematerialize
// it from the original global load -> weight fragments stay register-resident.
__device__ __forceinline__ f16x8 pin8h(f16x8 v) {
    union { f16x8 s; int i[4]; } u; u.s = v;
    const int a = (threadIdx.x & 63) << 2;
#pragma unroll
    for (int k = 0; k < 4; ++k) u.i[k] = __builtin_amdgcn_ds_bpermute(a, u.i[k]);
    return u.s;
}

// ---------------- K0: weights -> fp16 (WQ,WK,WV,WE) + bf16 (Wfc) + degree histogram ---
__global__ __launch_bounds__(256) void convert_hist_kernel(
    const float* __restrict__ w0, const float* __restrict__ w1,
    const float* __restrict__ w2, const float* __restrict__ w3,
    const float* __restrict__ w4, _Float16* __restrict__ wf,
    short* __restrict__ wfc,
    const int* __restrict__ eidx, int* __restrict__ deg)
{
    if (blockIdx.x < 320) {
        int i = blockIdx.x * 256 + threadIdx.x;      // 81920 threads
        int w = i >> 14, off = i & 16383;
        if (w < 4) {
            const float* src = (w == 0) ? w0 : (w == 1) ? w1 : (w == 2) ? w2 : w3;
            wf[i] = (_Float16)src[off];              // order: WQ, WK, WV, WE
        } else {
            wfc[off] = f2bf(w4[off]);
        }
    } else {
        int e = (blockIdx.x - 320) * 256 + threadIdx.x;
        if (e < EN) atomicAdd(&deg[eidx[e]], 1);
    }
}

// ---------------- parallel CSR scan: stage A (local prefix + block sums + deg hist) ---
__global__ __launch_bounds__(256) void scan_a_kernel(
    const int* __restrict__ deg, int* __restrict__ base,
    int* __restrict__ bsum, int* __restrict__ dhist)
{
    __shared__ int part[256];
    const int b = blockIdx.x, t = threadIdx.x;
    const int idx = b * 256 + t;                  // 98*256 = 25088 >= NN+1
    const int d = deg[idx];                       // deg zero-padded to 25088
    if (idx < NN) atomicAdd(&dhist[d < 63 ? d : 63], 1);
    part[t] = d;
    __syncthreads();
    for (int o = 1; o < 256; o <<= 1) {
        int v = (t >= o) ? part[t - o] : 0;
        __syncthreads();
        part[t] += v;
        __syncthreads();
    }
    base[idx] = part[t] - d;                      // exclusive local prefix
    if (t == 255) bsum[b] = part[255];
}

// ---------------- stage B: scan 98 block sums + 64 degree-hist buckets (1 tiny block) -
__global__ __launch_bounds__(128) void scan_b_kernel(
    const int* __restrict__ bsum, int* __restrict__ boff,
    const int* __restrict__ dhist, int* __restrict__ dbase2)
{
    __shared__ int s1[128], s2[128];
    const int t = threadIdx.x;
    const int v1 = (t < 98) ? bsum[t] : 0;
    const int v2 = (t < 64) ? dhist[t] : 0;
    s1[t] = v1; s2[t] = v2;
    __syncthreads();
    for (int o = 1; o < 128; o <<= 1) {
        int a = (t >= o) ? s1[t - o] : 0;
        int b = (t >= o) ? s2[t - o] : 0;
        __syncthreads();
        s1[t] += a; s2[t] += b;
        __syncthreads();
    }
    if (t < 98) boff[t] = s1[t] - v1;             // exclusive
    if (t < 64) dbase2[t] = s2[t] - v2;
}

// ---------------- stage C: absolute base + degree-sorted node order ----------------
__global__ __launch_bounds__(256) void scan_c_kernel(
    const int* __restrict__ deg, int* __restrict__ base,
    const int* __restrict__ boff, const int* __restrict__ dbase2,
    int* __restrict__ dcnt, int* __restrict__ nodeord)
{
    const int idx = blockIdx.x * 256 + threadIdx.x;   // 25088
    base[idx] += boff[idx >> 8];
    if (idx < NN) {
        const int d = deg[idx] < 63 ? deg[idx] : 63;
        const int r = dbase2[d] + atomicAdd(&dcnt[d], 1);
        nodeord[r] = idx;
    }
}

// writes pack[e] = {src, tgt, csr_pos, 0} and tgt_csr[csr_pos] = tgt
__global__ __launch_bounds__(256) void scatter_kernel(
    const int* __restrict__ eidx, const int* __restrict__ base,
    int* __restrict__ cnt, int4* __restrict__ pack, int* __restrict__ tgt_csr)
{
    int e = blockIdx.x * 256 + threadIdx.x;
    if (e < EN) {
        int s = eidx[e];
        int tg = eidx[EN + e];
        int p = base[s] + atomicAdd(&cnt[s], 1);
        pack[e] = make_int4(s, tg, p, 0);
        tgt_csr[p] = tg;
    }
}

// ---------------- K1: fused head-split projections, single-pass fp16 (Q, K, V) -------
// blockIdx.y: 0=Q, 1=K, 2=V. PERMUTED A-rows: lane (el,g) accumulates dims
// hw*32 + g*8 .. +8  -> output is ONE contiguous f16x8 (16B) store per lane.
__global__ __launch_bounds__(256, 4) void proj_all_kernel(
    const float* __restrict__ inQ, const float* __restrict__ inK,
    const float* __restrict__ inV, const _Float16* __restrict__ WfBase,
    _Float16* __restrict__ Qh, _Float16* __restrict__ Kh, _Float16* __restrict__ Vh)
{
    const int mode = blockIdx.y;
    const int lane = threadIdx.x & 63;
    const int hw = threadIdx.x >> 6;          // head / wave
    const int el = lane & 15;
    const int g  = lane >> 4;
    const int ntiles = (NN + 15) >> 4;

    const float* X = (mode == 0) ? inQ : (mode == 1) ? inK : inV;
    const _Float16* Wf = WfBase + mode * 16384;
    _Float16* P = (mode == 0) ? Qh : (mode == 1) ? Kh : Vh;

    f16x8 wf[2][4];
#pragma unroll
    for (int dtt = 0; dtt < 2; ++dtt)
#pragma unroll
        for (int kc = 0; kc < 4; ++kc) {
            const int r = hw * 32 + ((el >> 2) * 8) + dtt * 4 + (el & 3);  // permuted
            wf[dtt][kc] = pin8h(*(const f16x8*)(Wf + r * 128 + kc * 32 + g * 8));
        }

    for (int tile = blockIdx.x; tile < ntiles; tile += gridDim.x) {
        const int row = tile * 16 + el;
        const int rc = row < NN ? row : NN - 1;
        const float* xrow = X + (size_t)rc * 128;
        f32x4 acc0 = {}, acc1 = {};
#pragma unroll
        for (int kc = 0; kc < 4; ++kc) {
            const int kb = kc * 32 + g * 8;
            f32x4 x0 = *(const f32x4*)(xrow + kb);
            f32x4 x1 = *(const f32x4*)(xrow + kb + 4);
            f16x8 b;
#pragma unroll
            for (int j = 0; j < 4; ++j) { b[j] = (_Float16)x0[j]; b[4 + j] = (_Float16)x1[j]; }
            acc0 = __builtin_amdgcn_mfma_f32_16x16x32_f16(wf[0][kc], b, acc0, 0, 0, 0);
            acc1 = __builtin_amdgcn_mfma_f32_16x16x32_f16(wf[1][kc], b, acc1, 0, 0, 0);
        }
        if (row < NN) {
            f16x8 o;
#pragma unroll
            for (int j = 0; j < 4; ++j) {
                o[j]     = (_Float16)acc0[j];
                o[4 + j] = (_Float16)acc1[j];
            }
            *(f16x8*)(P + (size_t)row * 128 + hw * 32 + g * 8) = o;
        }
    }
}

// ---------------- K2a: 8-wave / 32-edge fp16 Ef-GEMM + score + exp (R18, unchanged) ---
__global__ __launch_bounds__(512, 2) void edge_score_kernel(
    const int4* __restrict__ pack, const float* __restrict__ efeat,
    const _Float16* __restrict__ Qh, const _Float16* __restrict__ Kh,
    const _Float16* __restrict__ WEf,
    float* __restrict__ attn_out, float* __restrict__ attn_csr)
{
    __shared__ _Float16 lds_e[2][32][136];   // [buf][edge][dim], 17.4 KB

    const int t    = threadIdx.x;
    const int lane = t & 63;
    const int w    = t >> 6;              // wave 0..7
    const int hw   = w & 3;               // head
    const int sub  = w >> 2;              // edge subtile 0/1
    const int el   = lane & 15;
    const int g    = lane >> 4;
    const int se   = t >> 4;              // staging: edge 0..31
    const int sd   = (t & 15) * 8;        // staging: dim
    const int NT   = EN / 32;             // 12500

    // pinned fp16 weight fragments, PERMUTED rows (32 regs)
    f16x8 wf[2][4];
#pragma unroll
    for (int dtt = 0; dtt < 2; ++dtt)
#pragma unroll
        for (int kc = 0; kc < 4; ++kc) {
            const int r = hw * 32 + ((el >> 2) * 8) + dtt * 4 + (el & 3);  // permuted
            wf[dtt][kc] = pin8h(*(const f16x8*)(WEf + r * 128 + kc * 32 + g * 8));
        }

    const int dbase = hw * 32 + g * 8;
    int tile = blockIdx.x;
    int4 pk = pack[(size_t)tile * 32 + sub * 16 + el];

    // prologue: synchronous stage tile0 -> LDS[0]
    {
        const float* p = efeat + ((size_t)tile * 32 + se) * 128 + sd;
        f32x4 a = *(const f32x4*)p;
        f32x4 b = *(const f32x4*)(p + 4);
        f16x8 h8;
#pragma unroll
        for (int j = 0; j < 4; ++j) {
            h8[j] = (_Float16)a[j];
            h8[4 + j] = (_Float16)b[j];
        }
        *(f16x8*)&lds_e[0][se][sd] = h8;
    }
    // preload tile1 data into registers (written to LDS at end of iteration 0)
    f32x4 eA, eB;
    int4 pk1;
    {
        const int t1 = tile + (int)gridDim.x;
        const int tl1 = (t1 < NT) ? t1 : tile;
        const float* np = efeat + ((size_t)tl1 * 32 + se) * 128 + sd;
        eA = *(const f32x4*)np;
        eB = *(const f32x4*)(np + 4);
        pk1 = pack[(size_t)tl1 * 32 + sub * 16 + el];
    }

    int buf = 0;
    while (true) {
        // A) fp16 gathers for CURRENT tile — one 16B load per operand per lane
        f16x8 q16 = *(const f16x8*)(Qh + (size_t)pk.x * 128 + dbase);
        f16x8 k16 = *(const f16x8*)(Kh + (size_t)pk.y * 128 + dbase);

        // B) issue efeat + pack loads for tile i+2 (consumed NEXT iteration at H)
        const int next = tile + (int)gridDim.x;
        const bool has_next = next < NT;
        const int n2 = next + (int)gridDim.x;
        const int tl2 = (n2 < NT) ? n2 : tile;
        const float* np2 = efeat + ((size_t)tl2 * 32 + se) * 128 + sd;
        f32x4 eAn = *(const f32x4*)np2;
        f32x4 eBn = *(const f32x4*)(np2 + 4);
        int4 pk2 = pack[(size_t)tl2 * 32 + sub * 16 + el];

        // C) barrier: order LDS double-buffer only — do NOT drain vmcnt
        asm volatile("s_waitcnt lgkmcnt(0)" ::: "memory");
        __builtin_amdgcn_s_barrier();
        __builtin_amdgcn_sched_barrier(0);

        // D) MFMA phase from LDS (lgkmcnt only): 8 fp16 MFMAs on this wave's subtile
        __builtin_amdgcn_s_setprio(1);
        f32x4 acc0 = {}, acc1 = {};
#pragma unroll
        for (int kc = 0; kc < 4; ++kc) {
            const int kb = kc * 32 + g * 8;
            f16x8 be = *(const f16x8*)&lds_e[buf][sub * 16 + el][kb];
            acc0 = __builtin_amdgcn_mfma_f32_16x16x32_f16(wf[0][kc], be, acc0, 0, 0, 0);
            acc1 = __builtin_amdgcn_mfma_f32_16x16x32_f16(wf[1][kc], be, acc1, 0, 0, 0);
        }
        __builtin_amdgcn_s_setprio(0);

        // E) combine: lane covers dims dbase..dbase+8 (acc0 = +0..4, acc1 = +4..8)
        float part = 0.f;
#pragma unroll
        for (int j = 0; j < 4; ++j) {
            part += (float)q16[j]     * (float)k16[j]     * acc0[j];
            part += (float)q16[4 + j] * (float)k16[4 + j] * acc1[j];
        }
        part += __shfl_xor(part, 16, 64);
        part += __shfl_xor(part, 32, 64);
        float sc = part * 0.17677669529663687f;     // 1/sqrt(32)
        sc = fminf(5.0f, fmaxf(-5.0f, sc));
        const float a = __expf(sc);

        const int edge = tile * 32 + sub * 16 + el;
        if (g == 0) {
            attn_out[(size_t)hw * EN + edge] = a;          // coalesced 64B per wave
            attn_csr[(size_t)pk.z * 4 + hw] = a;           // scattered 4B
        }

        if (!has_next) break;

        // H) write tile i+1 into LDS[buf^1] from eA/eB (loaded a FULL iteration ago)
        {
            f16x8 h8;
#pragma unroll
            for (int j = 0; j < 4; ++j) {
                h8[j] = (_Float16)eA[j];
                h8[4 + j] = (_Float16)eB[j];
            }
            *(f16x8*)&lds_e[buf ^ 1][se][sd] = h8;
        }

        // rotate pipeline state
        tile = next;
        pk = pk1;  pk1 = pk2;
        eA = eAn;  eB = eBn;
        buf ^= 1;
    }
}

// ---------------- K2b: per-node gather-reduce + W_fc matvec + residual + LN ----------
// Nodes processed in DEGREE-SORTED order (nodeord): a block's 32 node-groups have
// near-equal degree -> intra-block max ~= mean (was ~1.7x waste on Poisson(16)).
__global__ __launch_bounds__(512) void node_kernel(
    const int* __restrict__ nodeord,
    const int* __restrict__ base, const int* __restrict__ tgt_csr,
    const float* __restrict__ attn_csr, const _Float16* __restrict__ Vh,
    const short* __restrict__ Wfcb, const float* __restrict__ inQ,
    const float* __restrict__ gamma, const float* __restrict__ beta,
    float* __restrict__ y)
{
    __shared__ short wlds[128 * 136];   // padded: stride 136 bf16
    __shared__ float alds[32 * 132];    // padded: stride 132 f32

    const int t = threadIdx.x;
    // stage W_fc: thread handles row r=t>>2, cols (t&3)*32..+31
    {
        const int r = t >> 2, colb = (t & 3) * 32;
#pragma unroll
        for (int c = 0; c < 4; ++c) {
            bf16x8 w = *(const bf16x8*)(Wfcb + r * 128 + colb + c * 8);
            *(bf16x8*)(&wlds[r * 136 + colb + c * 8]) = w;
        }
    }

    const int n_l = t >> 4;             // 0..31
    const int el  = t & 15;
    const int ni = blockIdx.x * 32 + n_l;
    const int node = (ni < NN) ? nodeord[ni] : NN;

    int b0 = 0, b1 = 0;
    if (node < NN) { b0 = base[node]; b1 = base[node + 1]; }
    float acc[8] = {};
    float csum = 0.f;
    const int h = el >> 2;

    int p = b0;
    for (; p + 8 <= b1; p += 8) {      // unroll x8 for memory-level parallelism
        int   tg[8];
        float aa[8];
        f16x8 vv[8];
#pragma unroll
        for (int u = 0; u < 8; ++u) tg[u] = tgt_csr[p + u];
#pragma unroll
        for (int u = 0; u < 8; ++u) aa[u] = attn_csr[(size_t)(p + u) * 4 + h];
#pragma unroll
        for (int u = 0; u < 8; ++u) vv[u] = *(const f16x8*)(Vh + (size_t)tg[u] * 128 + el * 8);
#pragma unroll
        for (int u = 0; u < 8; ++u) {
            csum += aa[u];
#pragma unroll
            for (int j = 0; j < 8; ++j) acc[j] += aa[u] * (float)vv[u][j];
        }
    }
    for (; p < b1; ++p) {
        const int tg = tgt_csr[p];
        const float a = attn_csr[(size_t)p * 4 + h];
        f16x8 v = *(const f16x8*)(Vh + (size_t)tg * 128 + el * 8);
        csum += a;
#pragma unroll
        for (int j = 0; j < 8; ++j) acc[j] += a * (float)v[j];
    }

    const float invc = 1.0f / (csum + 1e-8f);
#pragma unroll
    for (int j = 0; j < 8; ++j) alds[n_l * 132 + el * 8 + j] = acc[j] * invc;
    __syncthreads();

    float fc[8] = {};
#pragma unroll 4
    for (int k0 = 0; k0 < 128; k0 += 8) {
        float a8[8];
#pragma unroll
        for (int j = 0; j < 8; ++j) a8[j] = alds[n_l * 132 + k0 + j];
#pragma unroll
        for (int i = 0; i < 8; ++i) {
            const int d = el + 16 * i;
            bf16x8 w = *(const bf16x8*)(&wlds[d * 136 + k0]);
#pragma unroll
            for (int j = 0; j < 8; ++j) fc[i] += a8[j] * bf2f(w[j]);
        }
    }

    if (node < NN) {
        float x[8];
        float s = 0.f, s2 = 0.f;
#pragma unroll
        for (int i = 0; i < 8; ++i) {
            const int d = el + 16 * i;
            x[i] = fc[i] + inQ[(size_t)node * 128 + d];
            s += x[i]; s2 += x[i] * x[i];
        }
        s  += __shfl_xor(s, 1, 64);  s2 += __shfl_xor(s2, 1, 64);
        s  += __shfl_xor(s, 2, 64);  s2 += __shfl_xor(s2, 2, 64);
        s  += __shfl_xor(s, 4, 64);  s2 += __shfl_xor(s2, 4, 64);
        s  += __shfl_xor(s, 8, 64);  s2 += __shfl_xor(s2, 8, 64);
        const float mu = s * (1.0f / 128.0f);
        const float var = s2 * (1.0f / 128.0f) - mu * mu;
        const float rstd = rsqrtf(var + 1e-5f);
#pragma unroll
        for (int i = 0; i < 8; ++i) {
            const int d = el + 16 * i;
            y[(size_t)node * 128 + d] = (x[i] - mu) * rstd * gamma[d] + beta[d];
        }
    }
}

// ---------------- launcher ----------------
extern "C" void kernel_launch(void* const* d_in, const int* in_sizes, int n_in,
                              void* d_out, int out_size, void* d_ws, size_t ws_size,
                              hipStream_t stream) {
    const int*   eidx  = (const int*)d_in[0];
    const float* efeat = (const float*)d_in[1];
    const float* inQ   = (const float*)d_in[2];
    const float* inK   = (const float*)d_in[3];
    const float* inV   = (const float*)d_in[4];
    const float* WQ    = (const float*)d_in[5];
    const float* WK    = (const float*)d_in[6];
    const float* WV    = (const float*)d_in[7];
    const float* WE    = (const float*)d_in[8];
    const float* Wfc   = (const float*)d_in[9];
    const float* gamma = (const float*)d_in[10];
    const float* beta  = (const float*)d_in[11];

    float* y = (float*)d_out;
    float* attn_out = y + (size_t)NN * 128;   // 3,200,000

    // ws layout (bytes):
    //   Qh fp16:               6,400,000 @ 0
    //   Kh fp16:               6,400,000 @ 6,400,000
    //   Vh fp16:               6,400,000 @ 12,800,000
    //   Wf fp16 (4x16384):       131,072 @ 19,200,000   (WQ,WK,WV,WE)
    //   Wfcb bf16 (16384):        32,768 @ 19,331,072
    //   attn_csr f32:          6,400,000 @ 19,363,840
    //   tgt_csr int:           1,600,000 @ 25,763,840
    //   pack int4:             6,400,000 @ 27,363,840
    //   deg int (25088):         100,352 @ 33,763,840   } zeroed
    //   cnt int (25088):         100,352 @ 33,864,192   } zeroed
    //   dhist int (64):              256 @ 33,964,544   } zeroed
    //   dcnt int (64):               256 @ 33,964,800   } zeroed
    //   base int (25088):        100,352 @ 33,965,056
    //   bsum int (128):              512 @ 34,065,408
    //   boff int (128):              512 @ 34,065,920
    //   dbase2 int (64):             256 @ 34,066,432
    //   nodeord int (25000):     100,000 @ 34,066,688  -> total 34,166,688
    char* ws = (char*)d_ws;
    _Float16* Qh   = (_Float16*)ws;
    _Float16* Kh   = (_Float16*)(ws + 6400000);
    _Float16* Vh   = (_Float16*)(ws + 12800000);
    _Float16* Wf   = (_Float16*)(ws + 19200000);
    short* Wfcb    = (short*)(ws + 19331072);
    float* attn_csr= (float*)(ws + 19363840);
    int*   tgt_csr = (int*)  (ws + 25763840);
    int4*  pack    = (int4*) (ws + 27363840);
    int*   deg     = (int*)  (ws + 33763840);
    int*   cnt     = (int*)  (ws + 33864192);
    int*   dhist   = (int*)  (ws + 33964544);
    int*   dcnt    = (int*)  (ws + 33964800);
    int*   base    = (int*)  (ws + 33965056);
    int*   bsum    = (int*)  (ws + 34065408);
    int*   boff    = (int*)  (ws + 34065920);
    int*   dbase2  = (int*)  (ws + 34066432);
    int*   nodeord = (int*)  (ws + 34066688);

    hipMemsetAsync(deg, 0, 201216, stream);   // deg + cnt + dhist + dcnt

    convert_hist_kernel<<<320 + (EN + 255) / 256, 256, 0, stream>>>(
        WQ, WK, WV, WE, Wfc, Wf, Wfcb, eidx, deg);
    scan_a_kernel<<<98, 256, 0, stream>>>(deg, base, bsum, dhist);
    scan_b_kernel<<<1, 128, 0, stream>>>(bsum, boff, dhist, dbase2);
    scan_c_kernel<<<98, 256, 0, stream>>>(deg, base, boff, dbase2, dcnt, nodeord);
    scatter_kernel<<<(EN + 255) / 256, 256, 0, stream>>>(eidx, base, cnt, pack, tgt_csr);

    dim3 pg(391, 3);
    proj_all_kernel<<<pg, 256, 0, stream>>>(inQ, inK, inV, Wf, Qh, Kh, Vh);

    edge_score_kernel<<<768, 512, 0, stream>>>(pack, efeat, Qh, Kh, Wf + 3 * 16384,
                                               attn_out, attn_csr);

    node_kernel<<<(NN + 31) / 32, 512, 0, stream>>>(nodeord, base, tgt_csr, attn_csr, Vh,
                                                    Wfcb, inQ, gamma, beta, y);
}

// Round 20
// 218.660 us; speedup vs baseline: 1.5492x; 1.5492x over previous
//
#include <hip/hip_runtime.h>
#include <hip/hip_bf16.h>
#include <cstdint>
#include <cstddef>

// Problem constants (B=1)
#define EN 400000   // edges
#define NN 25000    // nodes
// D=128, H=4, DK=DV=32

typedef __attribute__((ext_vector_type(8))) short bf16x8;
typedef __attribute__((ext_vector_type(4))) short bf16x4;
typedef __attribute__((ext_vector_type(4))) float f32x4;
typedef __attribute__((ext_vector_type(4))) _Float16 f16x4;
typedef __attribute__((ext_vector_type(8))) _Float16 f16x8;

__device__ __forceinline__ short f2bf(float f) {
    unsigned int u = __float_as_uint(f);
    u = (u + 0x7fffu + ((u >> 16) & 1u)) >> 16;   // RNE
    return (short)u;
}
__device__ __forceinline__ float bf2f(short s) {
    return __uint_as_float(((unsigned int)(unsigned short)s) << 16);
}

// Identity ds_bpermute: result is DS-defined, so the compiler cannot rematerialize
// it from the original global load -> weight fragments stay register-resident.
__device__ __forceinline__ f16x8 pin8h(f16x8 v) {
    union { f16x8 s; int i[4]; } u; u.s = v;
    const int a = (threadIdx.x & 63) << 2;
#pragma unroll
    for (int k = 0; k < 4; ++k) u.i[k] = __builtin_amdgcn_ds_bpermute(a, u.i[k]);
    return u.s;
}

// ---------------- K0: weights -> fp16 (WQ,WK,WV,WE) + bf16 (Wfc) + degree histogram ---
__global__ __launch_bounds__(256) void convert_hist_kernel(
    const float* __restrict__ w0, const float* __restrict__ w1,
    const float* __restrict__ w2, const float* __restrict__ w3,
    const float* __restrict__ w4, _Float16* __restrict__ wf,
    short* __restrict__ wfc,
    const int* __restrict__ eidx, int* __restrict__ deg)
{
    if (blockIdx.x < 320) {
        int i = blockIdx.x * 256 + threadIdx.x;      // 81920 threads
        int w = i >> 14, off = i & 16383;
        if (w < 4) {
            const float* src = (w == 0) ? w0 : (w == 1) ? w1 : (w == 2) ? w2 : w3;
            wf[i] = (_Float16)src[off];              // order: WQ, WK, WV, WE
        } else {
            wfc[off] = f2bf(w4[off]);
        }
    } else {
        int e = (blockIdx.x - 320) * 256 + threadIdx.x;
        if (e < EN) atomicAdd(&deg[eidx[e]], 1);
    }
}

// ---------------- CSR scan ----------------
__global__ __launch_bounds__(1024) void scan_kernel(
    const int* __restrict__ deg, int* __restrict__ base)
{
    __shared__ int part[1024];
    const int t = threadIdx.x;
    const int CH = 25;                       // 1024*25 = 25600 >= NN
    int loc[CH];
    int s = 0;
#pragma unroll
    for (int i = 0; i < CH; ++i) {
        int idx = t * CH + i;
        loc[i] = s;
        s += (idx < NN) ? deg[idx] : 0;
    }
    part[t] = s;
    __syncthreads();
    for (int d = 1; d < 1024; d <<= 1) {
        int v = (t >= d) ? part[t - d] : 0;
        __syncthreads();
        part[t] += v;
        __syncthreads();
    }
    int off = (t > 0) ? part[t - 1] : 0;
#pragma unroll
    for (int i = 0; i < CH; ++i) {
        int idx = t * CH + i;
        if (idx < NN) base[idx] = off + loc[i];
    }
    if (t == 1023) base[NN] = part[1023];
}

// writes pack[e] = {src, tgt, csr_pos, 0} and tgt_csr[csr_pos] = tgt
__global__ __launch_bounds__(256) void scatter_kernel(
    const int* __restrict__ eidx, const int* __restrict__ base,
    int* __restrict__ cnt, int4* __restrict__ pack, int* __restrict__ tgt_csr)
{
    int e = blockIdx.x * 256 + threadIdx.x;
    if (e < EN) {
        int s = eidx[e];
        int tg = eidx[EN + e];
        int p = base[s] + atomicAdd(&cnt[s], 1);
        pack[e] = make_int4(s, tg, p, 0);
        tgt_csr[p] = tg;
    }
}

// ---------------- K1: fused head-split projections, single-pass fp16 (Q, K, V) -------
// blockIdx.y: 0=Q, 1=K, 2=V. PERMUTED A-rows: lane el's A fragment holds W row
// hw*32 + (el>>2)*8 + dtt*4 + (el&3), so lane (el,g) accumulates dims
// hw*32 + g*8 + dtt*4 + j  -> output is ONE contiguous f16x8 (16B) store per lane.
__global__ __launch_bounds__(256, 4) void proj_all_kernel(
    const float* __restrict__ inQ, const float* __restrict__ inK,
    const float* __restrict__ inV, const _Float16* __restrict__ WfBase,
    _Float16* __restrict__ Qh, _Float16* __restrict__ Kh, _Float16* __restrict__ Vh)
{
    const int mode = blockIdx.y;
    const int lane = threadIdx.x & 63;
    const int hw = threadIdx.x >> 6;          // head / wave
    const int el = lane & 15;
    const int g  = lane >> 4;
    const int ntiles = (NN + 15) >> 4;

    const float* X = (mode == 0) ? inQ : (mode == 1) ? inK : inV;
    const _Float16* Wf = WfBase + mode * 16384;
    _Float16* P = (mode == 0) ? Qh : (mode == 1) ? Kh : Vh;

    f16x8 wf[2][4];
#pragma unroll
    for (int dtt = 0; dtt < 2; ++dtt)
#pragma unroll
        for (int kc = 0; kc < 4; ++kc) {
            const int r = hw * 32 + ((el >> 2) * 8) + dtt * 4 + (el & 3);  // permuted
            wf[dtt][kc] = pin8h(*(const f16x8*)(Wf + r * 128 + kc * 32 + g * 8));
        }

    for (int tile = blockIdx.x; tile < ntiles; tile += gridDim.x) {
        const int row = tile * 16 + el;
        const int rc = row < NN ? row : NN - 1;
        const float* xrow = X + (size_t)rc * 128;
        f32x4 acc0 = {}, acc1 = {};
#pragma unroll
        for (int kc = 0; kc < 4; ++kc) {
            const int kb = kc * 32 + g * 8;
            f32x4 x0 = *(const f32x4*)(xrow + kb);
            f32x4 x1 = *(const f32x4*)(xrow + kb + 4);
            f16x8 b;
#pragma unroll
            for (int j = 0; j < 4; ++j) { b[j] = (_Float16)x0[j]; b[4 + j] = (_Float16)x1[j]; }
            acc0 = __builtin_amdgcn_mfma_f32_16x16x32_f16(wf[0][kc], b, acc0, 0, 0, 0);
            acc1 = __builtin_amdgcn_mfma_f32_16x16x32_f16(wf[1][kc], b, acc1, 0, 0, 0);
        }
        if (row < NN) {
            // lane (el,g): acc0[j] = dim hw*32+g*8+j, acc1[j] = dim hw*32+g*8+4+j
            f16x8 o;
#pragma unroll
            for (int j = 0; j < 4; ++j) {
                o[j]     = (_Float16)acc0[j];
                o[4 + j] = (_Float16)acc1[j];
            }
            *(f16x8*)(P + (size_t)row * 128 + hw * 32 + g * 8) = o;
        }
    }
}

// ---------------- K2a: 8-wave / 32-edge fp16 Ef-GEMM + score + exp ----------------
// Permuted A-rows (see K1): lane (el,g) holds score-dims hw*32+g*8..+8, so the Q/K
// gathers are ONE contiguous f16x8 (16B) load each — 2 scattered VMEM instrs per
// wave-iter instead of 4, and 4 g-lanes cover a full 64B line (requests halved).
// Write-late staging + counted-vmcnt barrier retained.
__global__ __launch_bounds__(512, 2) void edge_score_kernel(
    const int4* __restrict__ pack, const float* __restrict__ efeat,
    const _Float16* __restrict__ Qh, const _Float16* __restrict__ Kh,
    const _Float16* __restrict__ WEf,
    float* __restrict__ attn_out, float* __restrict__ attn_csr)
{
    __shared__ _Float16 lds_e[2][32][136];   // [buf][edge][dim], 17.4 KB

    const int t    = threadIdx.x;
    const int lane = t & 63;
    const int w    = t >> 6;              // wave 0..7
    const int hw   = w & 3;               // head
    const int sub  = w >> 2;              // edge subtile 0/1
    const int el   = lane & 15;
    const int g    = lane >> 4;
    const int se   = t >> 4;              // staging: edge 0..31
    const int sd   = (t & 15) * 8;        // staging: dim
    const int NT   = EN / 32;             // 12500

    // pinned fp16 weight fragments, PERMUTED rows (32 regs)
    f16x8 wf[2][4];
#pragma unroll
    for (int dtt = 0; dtt < 2; ++dtt)
#pragma unroll
        for (int kc = 0; kc < 4; ++kc) {
            const int r = hw * 32 + ((el >> 2) * 8) + dtt * 4 + (el & 3);  // permuted
            wf[dtt][kc] = pin8h(*(const f16x8*)(WEf + r * 128 + kc * 32 + g * 8));
        }

    const int dbase = hw * 32 + g * 8;
    int tile = blockIdx.x;
    int4 pk = pack[(size_t)tile * 32 + sub * 16 + el];

    // prologue: synchronous stage tile0 -> LDS[0]
    {
        const float* p = efeat + ((size_t)tile * 32 + se) * 128 + sd;
        f32x4 a = *(const f32x4*)p;
        f32x4 b = *(const f32x4*)(p + 4);
        f16x8 h8;
#pragma unroll
        for (int j = 0; j < 4; ++j) {
            h8[j] = (_Float16)a[j];
            h8[4 + j] = (_Float16)b[j];
        }
        *(f16x8*)&lds_e[0][se][sd] = h8;
    }
    // preload tile1 data into registers (written to LDS at end of iteration 0)
    f32x4 eA, eB;
    int4 pk1;
    {
        const int t1 = tile + (int)gridDim.x;
        const int tl1 = (t1 < NT) ? t1 : tile;
        const float* np = efeat + ((size_t)tl1 * 32 + se) * 128 + sd;
        eA = *(const f32x4*)np;
        eB = *(const f32x4*)(np + 4);
        pk1 = pack[(size_t)tl1 * 32 + sub * 16 + el];
    }

    int buf = 0;
    while (true) {
        // A) fp16 gathers for CURRENT tile — one 16B load per operand per lane
        f16x8 q16 = *(const f16x8*)(Qh + (size_t)pk.x * 128 + dbase);
        f16x8 k16 = *(const f16x8*)(Kh + (size_t)pk.y * 128 + dbase);

        // B) issue efeat + pack loads for tile i+2 (consumed NEXT iteration at H)
        const int next = tile + (int)gridDim.x;
        const bool has_next = next < NT;
        const int n2 = next + (int)gridDim.x;
        const int tl2 = (n2 < NT) ? n2 : tile;
        const float* np2 = efeat + ((size_t)tl2 * 32 + se) * 128 + sd;
        f32x4 eAn = *(const f32x4*)np2;
        f32x4 eBn = *(const f32x4*)(np2 + 4);
        int4 pk2 = pack[(size_t)tl2 * 32 + sub * 16 + el];

        // C) barrier: order LDS double-buffer only — do NOT drain vmcnt
        asm volatile("s_waitcnt lgkmcnt(0)" ::: "memory");
        __builtin_amdgcn_s_barrier();
        __builtin_amdgcn_sched_barrier(0);

        // D) MFMA phase from LDS (lgkmcnt only): 8 fp16 MFMAs on this wave's subtile
        __builtin_amdgcn_s_setprio(1);
        f32x4 acc0 = {}, acc1 = {};
#pragma unroll
        for (int kc = 0; kc < 4; ++kc) {
            const int kb = kc * 32 + g * 8;
            f16x8 be = *(const f16x8*)&lds_e[buf][sub * 16 + el][kb];
            acc0 = __builtin_amdgcn_mfma_f32_16x16x32_f16(wf[0][kc], be, acc0, 0, 0, 0);
            acc1 = __builtin_amdgcn_mfma_f32_16x16x32_f16(wf[1][kc], be, acc1, 0, 0, 0);
        }
        __builtin_amdgcn_s_setprio(0);

        // E) combine: lane covers dims dbase..dbase+8 (acc0 = +0..4, acc1 = +4..8)
        float part = 0.f;
#pragma unroll
        for (int j = 0; j < 4; ++j) {
            part += (float)q16[j]     * (float)k16[j]     * acc0[j];
            part += (float)q16[4 + j] * (float)k16[4 + j] * acc1[j];
        }
        part += __shfl_xor(part, 16, 64);
        part += __shfl_xor(part, 32, 64);
        float sc = part * 0.17677669529663687f;     // 1/sqrt(32)
        sc = fminf(5.0f, fmaxf(-5.0f, sc));
        const float a = __expf(sc);

        const int edge = tile * 32 + sub * 16 + el;
        if (g == 0) {
            attn_out[(size_t)hw * EN + edge] = a;          // coalesced 64B per wave
            attn_csr[(size_t)pk.z * 4 + hw] = a;           // scattered 4B
        }

        if (!has_next) break;

        // H) write tile i+1 into LDS[buf^1] from eA/eB (loaded a FULL iteration ago)
        {
            f16x8 h8;
#pragma unroll
            for (int j = 0; j < 4; ++j) {
                h8[j] = (_Float16)eA[j];
                h8[4 + j] = (_Float16)eB[j];
            }
            *(f16x8*)&lds_e[buf ^ 1][se][sd] = h8;
        }

        // rotate pipeline state
        tile = next;
        pk = pk1;  pk1 = pk2;
        eA = eAn;  eB = eBn;
        buf ^= 1;
    }
}

// ---------------- K2b: per-node gather-reduce + W_fc matvec + residual + LN ----------
// 512 threads = 32 nodes/block: one W_fc LDS copy amortized 2x. V is fp16.
// Natural node order (contiguous CSR streaming + coalesced y/inQ) — degree-sorted
// indirection regressed 55% (R19): CSR/row locality beats intra-block balance.
__global__ __launch_bounds__(512) void node_kernel(
    const int* __restrict__ base, const int* __restrict__ tgt_csr,
    const float* __restrict__ attn_csr, const _Float16* __restrict__ Vh,
    const short* __restrict__ Wfcb, const float* __restrict__ inQ,
    const float* __restrict__ gamma, const float* __restrict__ beta,
    float* __restrict__ y)
{
    __shared__ short wlds[128 * 136];   // padded: stride 136 bf16
    __shared__ float alds[32 * 132];    // padded: stride 132 f32

    const int t = threadIdx.x;
    // stage W_fc: thread handles row r=t>>2, cols (t&3)*32..+31
    {
        const int r = t >> 2, colb = (t & 3) * 32;
#pragma unroll
        for (int c = 0; c < 4; ++c) {
            bf16x8 w = *(const bf16x8*)(Wfcb + r * 128 + colb + c * 8);
            *(bf16x8*)(&wlds[r * 136 + colb + c * 8]) = w;
        }
    }

    const int n_l = t >> 4;             // 0..31
    const int el  = t & 15;
    const int node = blockIdx.x * 32 + n_l;

    int b0 = 0, b1 = 0;
    if (node < NN) { b0 = base[node]; b1 = base[node + 1]; }
    float acc[8] = {};
    float csum = 0.f;
    const int h = el >> 2;

    int p = b0;
    for (; p + 8 <= b1; p += 8) {      // unroll x8 for memory-level parallelism
        int   tg[8];
        float aa[8];
        f16x8 vv[8];
#pragma unroll
        for (int u = 0; u < 8; ++u) tg[u] = tgt_csr[p + u];
#pragma unroll
        for (int u = 0; u < 8; ++u) aa[u] = attn_csr[(size_t)(p + u) * 4 + h];
#pragma unroll
        for (int u = 0; u < 8; ++u) vv[u] = *(const f16x8*)(Vh + (size_t)tg[u] * 128 + el * 8);
#pragma unroll
        for (int u = 0; u < 8; ++u) {
            csum += aa[u];
#pragma unroll
            for (int j = 0; j < 8; ++j) acc[j] += aa[u] * (float)vv[u][j];
        }
    }
    for (; p < b1; ++p) {
        const int tg = tgt_csr[p];
        const float a = attn_csr[(size_t)p * 4 + h];
        f16x8 v = *(const f16x8*)(Vh + (size_t)tg * 128 + el * 8);
        csum += a;
#pragma unroll
        for (int j = 0; j < 8; ++j) acc[j] += a * (float)v[j];
    }

    const float invc = 1.0f / (csum + 1e-8f);
#pragma unroll
    for (int j = 0; j < 8; ++j) alds[n_l * 132 + el * 8 + j] = acc[j] * invc;
    __syncthreads();

    float fc[8] = {};
#pragma unroll 4
    for (int k0 = 0; k0 < 128; k0 += 8) {
        float a8[8];
#pragma unroll
        for (int j = 0; j < 8; ++j) a8[j] = alds[n_l * 132 + k0 + j];
#pragma unroll
        for (int i = 0; i < 8; ++i) {
            const int d = el + 16 * i;
            bf16x8 w = *(const bf16x8*)(&wlds[d * 136 + k0]);
#pragma unroll
            for (int j = 0; j < 8; ++j) fc[i] += a8[j] * bf2f(w[j]);
        }
    }

    if (node < NN) {
        float x[8];
        float s = 0.f, s2 = 0.f;
#pragma unroll
        for (int i = 0; i < 8; ++i) {
            const int d = el + 16 * i;
            x[i] = fc[i] + inQ[(size_t)node * 128 + d];
            s += x[i]; s2 += x[i] * x[i];
        }
        s  += __shfl_xor(s, 1, 64);  s2 += __shfl_xor(s2, 1, 64);
        s  += __shfl_xor(s, 2, 64);  s2 += __shfl_xor(s2, 2, 64);
        s  += __shfl_xor(s, 4, 64);  s2 += __shfl_xor(s2, 4, 64);
        s  += __shfl_xor(s, 8, 64);  s2 += __shfl_xor(s2, 8, 64);
        const float mu = s * (1.0f / 128.0f);
        const float var = s2 * (1.0f / 128.0f) - mu * mu;
        const float rstd = rsqrtf(var + 1e-5f);
#pragma unroll
        for (int i = 0; i < 8; ++i) {
            const int d = el + 16 * i;
            y[(size_t)node * 128 + d] = (x[i] - mu) * rstd * gamma[d] + beta[d];
        }
    }
}

// ---------------- launcher ----------------
extern "C" void kernel_launch(void* const* d_in, const int* in_sizes, int n_in,
                              void* d_out, int out_size, void* d_ws, size_t ws_size,
                              hipStream_t stream) {
    const int*   eidx  = (const int*)d_in[0];
    const float* efeat = (const float*)d_in[1];
    const float* inQ   = (const float*)d_in[2];
    const float* inK   = (const float*)d_in[3];
    const float* inV   = (const float*)d_in[4];
    const float* WQ    = (const float*)d_in[5];
    const float* WK    = (const float*)d_in[6];
    const float* WV    = (const float*)d_in[7];
    const float* WE    = (const float*)d_in[8];
    const float* Wfc   = (const float*)d_in[9];
    const float* gamma = (const float*)d_in[10];
    const float* beta  = (const float*)d_in[11];

    float* y = (float*)d_out;
    float* attn_out = y + (size_t)NN * 128;   // 3,200,000

    // ws layout (bytes): same as R16-R18
    char* ws = (char*)d_ws;
    _Float16* Qh   = (_Float16*)ws;
    _Float16* Kh   = (_Float16*)(ws + 6400000);
    _Float16* Vh   = (_Float16*)(ws + 12800000);
    _Float16* Wf   = (_Float16*)(ws + 19200000);
    short* Wfcb    = (short*)(ws + 19331072);
    float* attn_csr= (float*)(ws + 19363840);
    int*   tgt_csr = (int*)  (ws + 25763840);
    int4*  pack    = (int4*) (ws + 27363840);
    int*   deg     = (int*)  (ws + 33763840);
    int*   cnt     = (int*)  (ws + 33864192);
    int*   base    = (int*)  (ws + 33964544);

    hipMemsetAsync(deg, 0, 200704, stream);   // deg + cnt

    convert_hist_kernel<<<320 + (EN + 255) / 256, 256, 0, stream>>>(
        WQ, WK, WV, WE, Wfc, Wf, Wfcb, eidx, deg);
    scan_kernel<<<1, 1024, 0, stream>>>(deg, base);
    scatter_kernel<<<(EN + 255) / 256, 256, 0, stream>>>(eidx, base, cnt, pack, tgt_csr);

    dim3 pg(391, 3);
    proj_all_kernel<<<pg, 256, 0, stream>>>(inQ, inK, inV, Wf, Qh, Kh, Vh);

    edge_score_kernel<<<768, 512, 0, stream>>>(pack, efeat, Qh, Kh, Wf + 3 * 16384,
                                               attn_out, attn_csr);

    node_kernel<<<(NN + 31) / 32, 512, 0, stream>>>(base, tgt_csr, attn_csr, Vh,
                                                    Wfcb, inQ, gamma, beta, y);
}

// Round 21
// 204.169 us; speedup vs baseline: 1.6592x; 1.0710x over previous
//
#include <hip/hip_runtime.h>
#include <hip/hip_bf16.h>
#include <cstdint>
#include <cstddef>

// Problem constants (B=1)
#define EN 400000   // edges
#define NN 25000    // nodes
// D=128, H=4, DK=DV=32

typedef __attribute__((ext_vector_type(8))) short bf16x8;
typedef __attribute__((ext_vector_type(4))) float f32x4;
typedef __attribute__((ext_vector_type(8))) _Float16 f16x8;

__device__ __forceinline__ short f2bf(float f) {
    unsigned int u = __float_as_uint(f);
    u = (u + 0x7fffu + ((u >> 16) & 1u)) >> 16;   // RNE
    return (short)u;
}
__device__ __forceinline__ float bf2f(short s) {
    return __uint_as_float(((unsigned int)(unsigned short)s) << 16);
}

// Identity ds_bpermute: result is DS-defined, so the compiler cannot rematerialize
// it from the original global load -> weight fragments stay register-resident.
__device__ __forceinline__ f16x8 pin8h(f16x8 v) {
    union { f16x8 s; int i[4]; } u; u.s = v;
    const int a = (threadIdx.x & 63) << 2;
#pragma unroll
    for (int k = 0; k < 4; ++k) u.i[k] = __builtin_amdgcn_ds_bpermute(a, u.i[k]);
    return u.s;
}

// ---------------- K0: weights -> fp16 (WQ,WK,WV,WE) + bf16 (Wfc) + degree histogram ---
__global__ __launch_bounds__(256) void convert_hist_kernel(
    const float* __restrict__ w0, const float* __restrict__ w1,
    const float* __restrict__ w2, const float* __restrict__ w3,
    const float* __restrict__ w4, _Float16* __restrict__ wf,
    short* __restrict__ wfc,
    const int* __restrict__ eidx, int* __restrict__ deg)
{
    if (blockIdx.x < 320) {
        int i = blockIdx.x * 256 + threadIdx.x;      // 81920 threads
        int w = i >> 14, off = i & 16383;
        if (w < 4) {
            const float* src = (w == 0) ? w0 : (w == 1) ? w1 : (w == 2) ? w2 : w3;
            wf[i] = (_Float16)src[off];              // order: WQ, WK, WV, WE
        } else {
            wfc[off] = f2bf(w4[off]);
        }
    } else {
        int e = (blockIdx.x - 320) * 256 + threadIdx.x;
        if (e < EN) atomicAdd(&deg[eidx[e]], 1);
    }
}

// ---------------- parallel CSR scan: stage A (local prefix + block sums) ----------
__global__ __launch_bounds__(256) void scan_a_kernel(
    const int* __restrict__ deg, int* __restrict__ base, int* __restrict__ bsum)
{
    __shared__ int part[256];
    const int b = blockIdx.x, t = threadIdx.x;
    const int idx = b * 256 + t;                  // 98*256 = 25088 >= NN+1
    const int d = deg[idx];                       // deg zero-padded to 25088
    part[t] = d;
    __syncthreads();
    for (int o = 1; o < 256; o <<= 1) {
        int v = (t >= o) ? part[t - o] : 0;
        __syncthreads();
        part[t] += v;
        __syncthreads();
    }
    base[idx] = part[t] - d;                      // exclusive local prefix
    if (t == 255) bsum[b] = part[255];
}

// ---------------- stage B: scan 98 block sums (1 tiny block) ----------------
__global__ __launch_bounds__(128) void scan_b_kernel(
    const int* __restrict__ bsum, int* __restrict__ boff)
{
    __shared__ int s1[128];
    const int t = threadIdx.x;
    const int v1 = (t < 98) ? bsum[t] : 0;
    s1[t] = v1;
    __syncthreads();
    for (int o = 1; o < 128; o <<= 1) {
        int a = (t >= o) ? s1[t - o] : 0;
        __syncthreads();
        s1[t] += a;
        __syncthreads();
    }
    if (t < 98) boff[t] = s1[t] - v1;             // exclusive
}

// ---------------- stage C: add block offsets ----------------
__global__ __launch_bounds__(256) void scan_c_kernel(
    int* __restrict__ base, const int* __restrict__ boff)
{
    const int idx = blockIdx.x * 256 + threadIdx.x;   // 25088
    base[idx] += boff[idx >> 8];
}

// writes pack[e] = {src, tgt, csr_pos, 0} and tgt_csr[csr_pos] = tgt
__global__ __launch_bounds__(256) void scatter_kernel(
    const int* __restrict__ eidx, const int* __restrict__ base,
    int* __restrict__ cnt, int4* __restrict__ pack, int* __restrict__ tgt_csr)
{
    int e = blockIdx.x * 256 + threadIdx.x;
    if (e < EN) {
        int s = eidx[e];
        int tg = eidx[EN + e];
        int p = base[s] + atomicAdd(&cnt[s], 1);
        pack[e] = make_int4(s, tg, p, 0);
        tgt_csr[p] = tg;
    }
}

// ---------------- K1: fused head-split projections, single-pass fp16 (Q, K, V) -------
// blockIdx.y: 0=Q, 1=K, 2=V. PERMUTED A-rows: lane (el,g) accumulates dims
// hw*32 + g*8 .. +8  -> output is ONE contiguous f16x8 (16B) store per lane.
__global__ __launch_bounds__(256, 4) void proj_all_kernel(
    const float* __restrict__ inQ, const float* __restrict__ inK,
    const float* __restrict__ inV, const _Float16* __restrict__ WfBase,
    _Float16* __restrict__ Qh, _Float16* __restrict__ Kh, _Float16* __restrict__ Vh)
{
    const int mode = blockIdx.y;
    const int lane = threadIdx.x & 63;
    const int hw = threadIdx.x >> 6;          // head / wave
    const int el = lane & 15;
    const int g  = lane >> 4;
    const int ntiles = (NN + 15) >> 4;

    const float* X = (mode == 0) ? inQ : (mode == 1) ? inK : inV;
    const _Float16* Wf = WfBase + mode * 16384;
    _Float16* P = (mode == 0) ? Qh : (mode == 1) ? Kh : Vh;

    f16x8 wf[2][4];
#pragma unroll
    for (int dtt = 0; dtt < 2; ++dtt)
#pragma unroll
        for (int kc = 0; kc < 4; ++kc) {
            const int r = hw * 32 + ((el >> 2) * 8) + dtt * 4 + (el & 3);  // permuted
            wf[dtt][kc] = pin8h(*(const f16x8*)(Wf + r * 128 + kc * 32 + g * 8));
        }

    for (int tile = blockIdx.x; tile < ntiles; tile += gridDim.x) {
        const int row = tile * 16 + el;
        const int rc = row < NN ? row : NN - 1;
        const float* xrow = X + (size_t)rc * 128;
        f32x4 acc0 = {}, acc1 = {};
#pragma unroll
        for (int kc = 0; kc < 4; ++kc) {
            const int kb = kc * 32 + g * 8;
            f32x4 x0 = *(const f32x4*)(xrow + kb);
            f32x4 x1 = *(const f32x4*)(xrow + kb + 4);
            f16x8 b;
#pragma unroll
            for (int j = 0; j < 4; ++j) { b[j] = (_Float16)x0[j]; b[4 + j] = (_Float16)x1[j]; }
            acc0 = __builtin_amdgcn_mfma_f32_16x16x32_f16(wf[0][kc], b, acc0, 0, 0, 0);
            acc1 = __builtin_amdgcn_mfma_f32_16x16x32_f16(wf[1][kc], b, acc1, 0, 0, 0);
        }
        if (row < NN) {
            f16x8 o;
#pragma unroll
            for (int j = 0; j < 4; ++j) {
                o[j]     = (_Float16)acc0[j];
                o[4 + j] = (_Float16)acc1[j];
            }
            *(f16x8*)(P + (size_t)row * 128 + hw * 32 + g * 8) = o;
        }
    }
}

// ---------------- K2a: 8-wave / 32-edge fp16 Ef-GEMM + score + exp (R18/R20) ---------
__global__ __launch_bounds__(512, 2) void edge_score_kernel(
    const int4* __restrict__ pack, const float* __restrict__ efeat,
    const _Float16* __restrict__ Qh, const _Float16* __restrict__ Kh,
    const _Float16* __restrict__ WEf,
    float* __restrict__ attn_out, float* __restrict__ attn_csr)
{
    __shared__ _Float16 lds_e[2][32][136];   // [buf][edge][dim], 17.4 KB

    const int t    = threadIdx.x;
    const int lane = t & 63;
    const int w    = t >> 6;              // wave 0..7
    const int hw   = w & 3;               // head
    const int sub  = w >> 2;              // edge subtile 0/1
    const int el   = lane & 15;
    const int g    = lane >> 4;
    const int se   = t >> 4;              // staging: edge 0..31
    const int sd   = (t & 15) * 8;        // staging: dim
    const int NT   = EN / 32;             // 12500

    // pinned fp16 weight fragments, PERMUTED rows (32 regs)
    f16x8 wf[2][4];
#pragma unroll
    for (int dtt = 0; dtt < 2; ++dtt)
#pragma unroll
        for (int kc = 0; kc < 4; ++kc) {
            const int r = hw * 32 + ((el >> 2) * 8) + dtt * 4 + (el & 3);  // permuted
            wf[dtt][kc] = pin8h(*(const f16x8*)(WEf + r * 128 + kc * 32 + g * 8));
        }

    const int dbase = hw * 32 + g * 8;
    int tile = blockIdx.x;
    int4 pk = pack[(size_t)tile * 32 + sub * 16 + el];

    // prologue: synchronous stage tile0 -> LDS[0]
    {
        const float* p = efeat + ((size_t)tile * 32 + se) * 128 + sd;
        f32x4 a = *(const f32x4*)p;
        f32x4 b = *(const f32x4*)(p + 4);
        f16x8 h8;
#pragma unroll
        for (int j = 0; j < 4; ++j) {
            h8[j] = (_Float16)a[j];
            h8[4 + j] = (_Float16)b[j];
        }
        *(f16x8*)&lds_e[0][se][sd] = h8;
    }
    // preload tile1 data into registers (written to LDS at end of iteration 0)
    f32x4 eA, eB;
    int4 pk1;
    {
        const int t1 = tile + (int)gridDim.x;
        const int tl1 = (t1 < NT) ? t1 : tile;
        const float* np = efeat + ((size_t)tl1 * 32 + se) * 128 + sd;
        eA = *(const f32x4*)np;
        eB = *(const f32x4*)(np + 4);
        pk1 = pack[(size_t)tl1 * 32 + sub * 16 + el];
    }

    int buf = 0;
    while (true) {
        // A) fp16 gathers for CURRENT tile — one 16B load per operand per lane
        f16x8 q16 = *(const f16x8*)(Qh + (size_t)pk.x * 128 + dbase);
        f16x8 k16 = *(const f16x8*)(Kh + (size_t)pk.y * 128 + dbase);

        // B) issue efeat + pack loads for tile i+2 (consumed NEXT iteration at H)
        const int next = tile + (int)gridDim.x;
        const bool has_next = next < NT;
        const int n2 = next + (int)gridDim.x;
        const int tl2 = (n2 < NT) ? n2 : tile;
        const float* np2 = efeat + ((size_t)tl2 * 32 + se) * 128 + sd;
        f32x4 eAn = *(const f32x4*)np2;
        f32x4 eBn = *(const f32x4*)(np2 + 4);
        int4 pk2 = pack[(size_t)tl2 * 32 + sub * 16 + el];

        // C) barrier: order LDS double-buffer only — do NOT drain vmcnt
        asm volatile("s_waitcnt lgkmcnt(0)" ::: "memory");
        __builtin_amdgcn_s_barrier();
        __builtin_amdgcn_sched_barrier(0);

        // D) MFMA phase from LDS (lgkmcnt only): 8 fp16 MFMAs on this wave's subtile
        __builtin_amdgcn_s_setprio(1);
        f32x4 acc0 = {}, acc1 = {};
#pragma unroll
        for (int kc = 0; kc < 4; ++kc) {
            const int kb = kc * 32 + g * 8;
            f16x8 be = *(const f16x8*)&lds_e[buf][sub * 16 + el][kb];
            acc0 = __builtin_amdgcn_mfma_f32_16x16x32_f16(wf[0][kc], be, acc0, 0, 0, 0);
            acc1 = __builtin_amdgcn_mfma_f32_16x16x32_f16(wf[1][kc], be, acc1, 0, 0, 0);
        }
        __builtin_amdgcn_s_setprio(0);

        // E) combine: lane covers dims dbase..dbase+8 (acc0 = +0..4, acc1 = +4..8)
        float part = 0.f;
#pragma unroll
        for (int j = 0; j < 4; ++j) {
            part += (float)q16[j]     * (float)k16[j]     * acc0[j];
            part += (float)q16[4 + j] * (float)k16[4 + j] * acc1[j];
        }
        part += __shfl_xor(part, 16, 64);
        part += __shfl_xor(part, 32, 64);
        float sc = part * 0.17677669529663687f;     // 1/sqrt(32)
        sc = fminf(5.0f, fmaxf(-5.0f, sc));
        const float a = __expf(sc);

        const int edge = tile * 32 + sub * 16 + el;
        if (g == 0) {
            attn_out[(size_t)hw * EN + edge] = a;          // coalesced 64B per wave
            attn_csr[(size_t)pk.z * 4 + hw] = a;           // scattered 4B
        }

        if (!has_next) break;

        // H) write tile i+1 into LDS[buf^1] from eA/eB (loaded a FULL iteration ago)
        {
            f16x8 h8;
#pragma unroll
            for (int j = 0; j < 4; ++j) {
                h8[j] = (_Float16)eA[j];
                h8[4 + j] = (_Float16)eB[j];
            }
            *(f16x8*)&lds_e[buf ^ 1][se][sd] = h8;
        }

        // rotate pipeline state
        tile = next;
        pk = pk1;  pk1 = pk2;
        eA = eAn;  eB = eBn;
        buf ^= 1;
    }
}

// ---------------- K2b: per-node gather-reduce + W_fc matvec + residual + LN ----------
// 512 threads = 32 nodes/block, NATURAL node order (R19's degree-sorted indirection
// regressed 55%: CSR/row locality beats intra-block balance).
__global__ __launch_bounds__(512) void node_kernel(
    const int* __restrict__ base, const int* __restrict__ tgt_csr,
    const float* __restrict__ attn_csr, const _Float16* __restrict__ Vh,
    const short* __restrict__ Wfcb, const float* __restrict__ inQ,
    const float* __restrict__ gamma, const float* __restrict__ beta,
    float* __restrict__ y)
{
    __shared__ short wlds[128 * 136];   // padded: stride 136 bf16
    __shared__ float alds[32 * 132];    // padded: stride 132 f32

    const int t = threadIdx.x;
    // stage W_fc: thread handles row r=t>>2, cols (t&3)*32..+31
    {
        const int r = t >> 2, colb = (t & 3) * 32;
#pragma unroll
        for (int c = 0; c < 4; ++c) {
            bf16x8 w = *(const bf16x8*)(Wfcb + r * 128 + colb + c * 8);
            *(bf16x8*)(&wlds[r * 136 + colb + c * 8]) = w;
        }
    }

    const int n_l = t >> 4;             // 0..31
    const int el  = t & 15;
    const int node = blockIdx.x * 32 + n_l;

    int b0 = 0, b1 = 0;
    if (node < NN) { b0 = base[node]; b1 = base[node + 1]; }
    float acc[8] = {};
    float csum = 0.f;
    const int h = el >> 2;

    int p = b0;
    for (; p + 8 <= b1; p += 8) {      // unroll x8 for memory-level parallelism
        int   tg[8];
        float aa[8];
        f16x8 vv[8];
#pragma unroll
        for (int u = 0; u < 8; ++u) tg[u] = tgt_csr[p + u];
#pragma unroll
        for (int u = 0; u < 8; ++u) aa[u] = attn_csr[(size_t)(p + u) * 4 + h];
#pragma unroll
        for (int u = 0; u < 8; ++u) vv[u] = *(const f16x8*)(Vh + (size_t)tg[u] * 128 + el * 8);
#pragma unroll
        for (int u = 0; u < 8; ++u) {
            csum += aa[u];
#pragma unroll
            for (int j = 0; j < 8; ++j) acc[j] += aa[u] * (float)vv[u][j];
        }
    }
    for (; p < b1; ++p) {
        const int tg = tgt_csr[p];
        const float a = attn_csr[(size_t)p * 4 + h];
        f16x8 v = *(const f16x8*)(Vh + (size_t)tg * 128 + el * 8);
        csum += a;
#pragma unroll
        for (int j = 0; j < 8; ++j) acc[j] += a * (float)v[j];
    }

    const float invc = 1.0f / (csum + 1e-8f);
#pragma unroll
    for (int j = 0; j < 8; ++j) alds[n_l * 132 + el * 8 + j] = acc[j] * invc;
    __syncthreads();

    float fc[8] = {};
#pragma unroll 4
    for (int k0 = 0; k0 < 128; k0 += 8) {
        float a8[8];
#pragma unroll
        for (int j = 0; j < 8; ++j) a8[j] = alds[n_l * 132 + k0 + j];
#pragma unroll
        for (int i = 0; i < 8; ++i) {
            const int d = el + 16 * i;
            bf16x8 w = *(const bf16x8*)(&wlds[d * 136 + k0]);
#pragma unroll
            for (int j = 0; j < 8; ++j) fc[i] += a8[j] * bf2f(w[j]);
        }
    }

    if (node < NN) {
        float x[8];
        float s = 0.f, s2 = 0.f;
#pragma unroll
        for (int i = 0; i < 8; ++i) {
            const int d = el + 16 * i;
            x[i] = fc[i] + inQ[(size_t)node * 128 + d];
            s += x[i]; s2 += x[i] * x[i];
        }
        s  += __shfl_xor(s, 1, 64);  s2 += __shfl_xor(s2, 1, 64);
        s  += __shfl_xor(s, 2, 64);  s2 += __shfl_xor(s2, 2, 64);
        s  += __shfl_xor(s, 4, 64);  s2 += __shfl_xor(s2, 4, 64);
        s  += __shfl_xor(s, 8, 64);  s2 += __shfl_xor(s2, 8, 64);
        const float mu = s * (1.0f / 128.0f);
        const float var = s2 * (1.0f / 128.0f) - mu * mu;
        const float rstd = rsqrtf(var + 1e-5f);
#pragma unroll
        for (int i = 0; i < 8; ++i) {
            const int d = el + 16 * i;
            y[(size_t)node * 128 + d] = (x[i] - mu) * rstd * gamma[d] + beta[d];
        }
    }
}

// ---------------- launcher ----------------
extern "C" void kernel_launch(void* const* d_in, const int* in_sizes, int n_in,
                              void* d_out, int out_size, void* d_ws, size_t ws_size,
                              hipStream_t stream) {
    const int*   eidx  = (const int*)d_in[0];
    const float* efeat = (const float*)d_in[1];
    const float* inQ   = (const float*)d_in[2];
    const float* inK   = (const float*)d_in[3];
    const float* inV   = (const float*)d_in[4];
    const float* WQ    = (const float*)d_in[5];
    const float* WK    = (const float*)d_in[6];
    const float* WV    = (const float*)d_in[7];
    const float* WE    = (const float*)d_in[8];
    const float* Wfc   = (const float*)d_in[9];
    const float* gamma = (const float*)d_in[10];
    const float* beta  = (const float*)d_in[11];

    float* y = (float*)d_out;
    float* attn_out = y + (size_t)NN * 128;   // 3,200,000

    // ws layout (bytes):
    //   Qh fp16:               6,400,000 @ 0
    //   Kh fp16:               6,400,000 @ 6,400,000
    //   Vh fp16:               6,400,000 @ 12,800,000
    //   Wf fp16 (4x16384):       131,072 @ 19,200,000   (WQ,WK,WV,WE)
    //   Wfcb bf16 (16384):        32,768 @ 19,331,072
    //   attn_csr f32:          6,400,000 @ 19,363,840
    //   tgt_csr int:           1,600,000 @ 25,763,840
    //   pack int4:             6,400,000 @ 27,363,840
    //   deg int (25088):         100,352 @ 33,763,840   } zeroed
    //   cnt int (25088):         100,352 @ 33,864,192   } zeroed
    //   base int (25088):        100,352 @ 33,964,544
    //   bsum int (128):              512 @ 34,064,896
    //   boff int (128):              512 @ 34,065,408  -> total 34,065,920
    char* ws = (char*)d_ws;
    _Float16* Qh   = (_Float16*)ws;
    _Float16* Kh   = (_Float16*)(ws + 6400000);
    _Float16* Vh   = (_Float16*)(ws + 12800000);
    _Float16* Wf   = (_Float16*)(ws + 19200000);
    short* Wfcb    = (short*)(ws + 19331072);
    float* attn_csr= (float*)(ws + 19363840);
    int*   tgt_csr = (int*)  (ws + 25763840);
    int4*  pack    = (int4*) (ws + 27363840);
    int*   deg     = (int*)  (ws + 33763840);
    int*   cnt     = (int*)  (ws + 33864192);
    int*   base    = (int*)  (ws + 33964544);
    int*   bsum    = (int*)  (ws + 34064896);
    int*   boff    = (int*)  (ws + 34065408);

    hipMemsetAsync(deg, 0, 200704, stream);   // deg + cnt

    convert_hist_kernel<<<320 + (EN + 255) / 256, 256, 0, stream>>>(
        WQ, WK, WV, WE, Wfc, Wf, Wfcb, eidx, deg);
    scan_a_kernel<<<98, 256, 0, stream>>>(deg, base, bsum);
    scan_b_kernel<<<1, 128, 0, stream>>>(bsum, boff);
    scan_c_kernel<<<98, 256, 0, stream>>>(base, boff);
    scatter_kernel<<<(EN + 255) / 256, 256, 0, stream>>>(eidx, base, cnt, pack, tgt_csr);

    dim3 pg(391, 3);
    proj_all_kernel<<<pg, 256, 0, stream>>>(inQ, inK, inV, Wf, Qh, Kh, Vh);

    edge_score_kernel<<<768, 512, 0, stream>>>(pack, efeat, Qh, Kh, Wf + 3 * 16384,
                                               attn_out, attn_csr);

    node_kernel<<<(NN + 31) / 32, 512, 0, stream>>>(base, tgt_csr, attn_csr, Vh,
                                                    Wfcb, inQ, gamma, beta, y);
}

// Round 22
// 203.772 us; speedup vs baseline: 1.6624x; 1.0019x over previous
//
#include <hip/hip_runtime.h>
#include <hip/hip_bf16.h>
#include <cstdint>
#include <cstddef>

// Problem constants (B=1)
#define EN 400000   // edges
#define NN 25000    // nodes
// D=128, H=4, DK=DV=32

typedef __attribute__((ext_vector_type(8))) short bf16x8;
typedef __attribute__((ext_vector_type(4))) float f32x4;
typedef __attribute__((ext_vector_type(8))) _Float16 f16x8;

__device__ __forceinline__ short f2bf(float f) {
    unsigned int u = __float_as_uint(f);
    u = (u + 0x7fffu + ((u >> 16) & 1u)) >> 16;   // RNE
    return (short)u;
}
__device__ __forceinline__ float bf2f(short s) {
    return __uint_as_float(((unsigned int)(unsigned short)s) << 16);
}

// Identity ds_bpermute: result is DS-defined, so the compiler cannot rematerialize
// it from the original global load -> weight fragments stay register-resident.
__device__ __forceinline__ f16x8 pin8h(f16x8 v) {
    union { f16x8 s; int i[4]; } u; u.s = v;
    const int a = (threadIdx.x & 63) << 2;
#pragma unroll
    for (int k = 0; k < 4; ++k) u.i[k] = __builtin_amdgcn_ds_bpermute(a, u.i[k]);
    return u.s;
}

// ---------------- K0: weights -> fp16 (WQ,WK,WV,WE) + bf16 (Wfc) + degree histogram ---
__global__ __launch_bounds__(256) void convert_hist_kernel(
    const float* __restrict__ w0, const float* __restrict__ w1,
    const float* __restrict__ w2, const float* __restrict__ w3,
    const float* __restrict__ w4, _Float16* __restrict__ wf,
    short* __restrict__ wfc,
    const int* __restrict__ eidx, int* __restrict__ deg)
{
    if (blockIdx.x < 320) {
        int i = blockIdx.x * 256 + threadIdx.x;      // 81920 threads
        int w = i >> 14, off = i & 16383;
        if (w < 4) {
            const float* src = (w == 0) ? w0 : (w == 1) ? w1 : (w == 2) ? w2 : w3;
            wf[i] = (_Float16)src[off];              // order: WQ, WK, WV, WE
        } else {
            wfc[off] = f2bf(w4[off]);
        }
    } else {
        int e = (blockIdx.x - 320) * 256 + threadIdx.x;
        if (e < EN) atomicAdd(&deg[eidx[e]], 1);
    }
}

// ---------------- parallel CSR scan: stage A (local prefix + block sums) ----------
__global__ __launch_bounds__(256) void scan_a_kernel(
    const int* __restrict__ deg, int* __restrict__ base, int* __restrict__ bsum)
{
    __shared__ int part[256];
    const int b = blockIdx.x, t = threadIdx.x;
    const int idx = b * 256 + t;                  // 98*256 = 25088 >= NN+1
    const int d = deg[idx];                       // deg zero-padded to 25088
    part[t] = d;
    __syncthreads();
    for (int o = 1; o < 256; o <<= 1) {
        int v = (t >= o) ? part[t - o] : 0;
        __syncthreads();
        part[t] += v;
        __syncthreads();
    }
    base[idx] = part[t] - d;                      // exclusive LOCAL prefix (boff applied later)
    if (t == 255) bsum[b] = part[255];
}

// ---------------- stage B: scan 98 block sums (1 tiny block) ----------------
__global__ __launch_bounds__(128) void scan_b_kernel(
    const int* __restrict__ bsum, int* __restrict__ boff)
{
    __shared__ int s1[128];
    const int t = threadIdx.x;
    const int v1 = (t < 98) ? bsum[t] : 0;
    s1[t] = v1;
    __syncthreads();
    for (int o = 1; o < 128; o <<= 1) {
        int a = (t >= o) ? s1[t - o] : 0;
        __syncthreads();
        s1[t] += a;
        __syncthreads();
    }
    if (t < 98) boff[t] = s1[t] - v1;             // exclusive
}

// scatter applies boff inline (scan stage C fused away). Also finalizes base[] in
// global so node_kernel sees absolute offsets.
__global__ __launch_bounds__(256) void scatter_kernel(
    const int* __restrict__ eidx, int* __restrict__ base,
    const int* __restrict__ boff,
    int* __restrict__ cnt, int4* __restrict__ pack, int* __restrict__ tgt_csr)
{
    int e = blockIdx.x * 256 + threadIdx.x;
    // finalize base for node_kernel: first 25088 threads add their block offset
    if (e < 25088) base[e] += boff[e >> 8];
    if (e < EN) {
        int s = eidx[e];
        int tg = eidx[EN + e];
        // base[s] may or may not be finalized yet (grid-wide race) -> recompute locally
        // from the pre-finalized value is unsafe; instead use atomicAdd on cnt plus the
        // known decomposition: absolute = local + boff. Read local ONCE via __ldg-style
        // load is racy with the += above. Solution: compute absolute from scratch:
        // NOTE: the += above only runs in this same kernel; to stay race-free we simply
        // DON'T read base[s] here, but rebuild it: impossible without the local value.
        // Hence: defer the edge work until after a device-scope sync is NOT available.
        // => keep edge scatter reading the ORIGINAL local base via a separate copy-free
        // trick: boff is idempotent per s, so absolute = (local prefix) + boff[s>>8].
        // We read base[s] with a volatile load and detect whether the += already landed
        // is NOT possible. SAFE FALLBACK: this kernel reads base2 (untouched local) --
        // see launcher: we pass base as both, but the += writes go to the SAME array.
        // To avoid the race entirely, the += is applied only by blocks >= EN/256 range?
        // Simplest correct form: do not fuse the += here; compute absolute directly:
        int p = base[s];                           // may be local or absolute (race!)
        (void)p;
        // -- replaced below by race-free path --
    }
}

// race-free fused scatter: reads LOCAL base + boff, writes absolute pos; base is
// finalized by a separate tiny pass embedded in node-launch-free scan_b grid? No —
// keep it simple and correct: finalize base in scan_b's grid (it has spare threads).
__global__ __launch_bounds__(256) void scatter2_kernel(
    const int* __restrict__ eidx, const int* __restrict__ base_local,
    const int* __restrict__ boff,
    int* __restrict__ cnt, int4* __restrict__ pack, int* __restrict__ tgt_csr,
    int* __restrict__ base_abs)
{
    int e = blockIdx.x * 256 + threadIdx.x;
    if (e < 25088) base_abs[e] = base_local[e] + boff[e >> 8];
    if (e < EN) {
        int s = eidx[e];
        int tg = eidx[EN + e];
        int p = base_local[s] + boff[s >> 8] + atomicAdd(&cnt[s], 1);
        pack[e] = make_int4(s, tg, p, 0);
        tgt_csr[p] = tg;
    }
}

// ---------------- K1: fused head-split projections, single-pass fp16 (Q, K, V) -------
// blockIdx.y: 0=Q, 1=K, 2=V. PERMUTED A-rows: lane (el,g) accumulates dims
// hw*32 + g*8 .. +8  -> output is ONE contiguous f16x8 (16B) store per lane.
__global__ __launch_bounds__(256, 4) void proj_all_kernel(
    const float* __restrict__ inQ, const float* __restrict__ inK,
    const float* __restrict__ inV, const _Float16* __restrict__ WfBase,
    _Float16* __restrict__ Qh, _Float16* __restrict__ Kh, _Float16* __restrict__ Vh)
{
    const int mode = blockIdx.y;
    const int lane = threadIdx.x & 63;
    const int hw = threadIdx.x >> 6;          // head / wave
    const int el = lane & 15;
    const int g  = lane >> 4;
    const int ntiles = (NN + 15) >> 4;

    const float* X = (mode == 0) ? inQ : (mode == 1) ? inK : inV;
    const _Float16* Wf = WfBase + mode * 16384;
    _Float16* P = (mode == 0) ? Qh : (mode == 1) ? Kh : Vh;

    f16x8 wf[2][4];
#pragma unroll
    for (int dtt = 0; dtt < 2; ++dtt)
#pragma unroll
        for (int kc = 0; kc < 4; ++kc) {
            const int r = hw * 32 + ((el >> 2) * 8) + dtt * 4 + (el & 3);  // permuted
            wf[dtt][kc] = pin8h(*(const f16x8*)(Wf + r * 128 + kc * 32 + g * 8));
        }

    for (int tile = blockIdx.x; tile < ntiles; tile += gridDim.x) {
        const int row = tile * 16 + el;
        const int rc = row < NN ? row : NN - 1;
        const float* xrow = X + (size_t)rc * 128;
        f32x4 acc0 = {}, acc1 = {};
#pragma unroll
        for (int kc = 0; kc < 4; ++kc) {
            const int kb = kc * 32 + g * 8;
            f32x4 x0 = *(const f32x4*)(xrow + kb);
            f32x4 x1 = *(const f32x4*)(xrow + kb + 4);
            f16x8 b;
#pragma unroll
            for (int j = 0; j < 4; ++j) { b[j] = (_Float16)x0[j]; b[4 + j] = (_Float16)x1[j]; }
            acc0 = __builtin_amdgcn_mfma_f32_16x16x32_f16(wf[0][kc], b, acc0, 0, 0, 0);
            acc1 = __builtin_amdgcn_mfma_f32_16x16x32_f16(wf[1][kc], b, acc1, 0, 0, 0);
        }
        if (row < NN) {
            f16x8 o;
#pragma unroll
            for (int j = 0; j < 4; ++j) {
                o[j]     = (_Float16)acc0[j];
                o[4 + j] = (_Float16)acc1[j];
            }
            *(f16x8*)(P + (size_t)row * 128 + hw * 32 + g * 8) = o;
        }
    }
}

// ---------------- K2a: 8-wave / 32-edge fp16 Ef-GEMM + score + exp (R18/R20/R21) ------
__global__ __launch_bounds__(512, 2) void edge_score_kernel(
    const int4* __restrict__ pack, const float* __restrict__ efeat,
    const _Float16* __restrict__ Qh, const _Float16* __restrict__ Kh,
    const _Float16* __restrict__ WEf,
    float* __restrict__ attn_out, float* __restrict__ attn_csr)
{
    __shared__ _Float16 lds_e[2][32][136];   // [buf][edge][dim], 17.4 KB

    const int t    = threadIdx.x;
    const int lane = t & 63;
    const int w    = t >> 6;              // wave 0..7
    const int hw   = w & 3;               // head
    const int sub  = w >> 2;              // edge subtile 0/1
    const int el   = lane & 15;
    const int g    = lane >> 4;
    const int se   = t >> 4;              // staging: edge 0..31
    const int sd   = (t & 15) * 8;        // staging: dim
    const int NT   = EN / 32;             // 12500

    // pinned fp16 weight fragments, PERMUTED rows (32 regs)
    f16x8 wf[2][4];
#pragma unroll
    for (int dtt = 0; dtt < 2; ++dtt)
#pragma unroll
        for (int kc = 0; kc < 4; ++kc) {
            const int r = hw * 32 + ((el >> 2) * 8) + dtt * 4 + (el & 3);  // permuted
            wf[dtt][kc] = pin8h(*(const f16x8*)(WEf + r * 128 + kc * 32 + g * 8));
        }

    const int dbase = hw * 32 + g * 8;
    int tile = blockIdx.x;
    int4 pk = pack[(size_t)tile * 32 + sub * 16 + el];

    // prologue: synchronous stage tile0 -> LDS[0]
    {
        const float* p = efeat + ((size_t)tile * 32 + se) * 128 + sd;
        f32x4 a = *(const f32x4*)p;
        f32x4 b = *(const f32x4*)(p + 4);
        f16x8 h8;
#pragma unroll
        for (int j = 0; j < 4; ++j) {
            h8[j] = (_Float16)a[j];
            h8[4 + j] = (_Float16)b[j];
        }
        *(f16x8*)&lds_e[0][se][sd] = h8;
    }
    // preload tile1 data into registers (written to LDS at end of iteration 0)
    f32x4 eA, eB;
    int4 pk1;
    {
        const int t1 = tile + (int)gridDim.x;
        const int tl1 = (t1 < NT) ? t1 : tile;
        const float* np = efeat + ((size_t)tl1 * 32 + se) * 128 + sd;
        eA = *(const f32x4*)np;
        eB = *(const f32x4*)(np + 4);
        pk1 = pack[(size_t)tl1 * 32 + sub * 16 + el];
    }

    int buf = 0;
    while (true) {
        // A) fp16 gathers for CURRENT tile — one 16B load per operand per lane
        f16x8 q16 = *(const f16x8*)(Qh + (size_t)pk.x * 128 + dbase);
        f16x8 k16 = *(const f16x8*)(Kh + (size_t)pk.y * 128 + dbase);

        // B) issue efeat + pack loads for tile i+2 (consumed NEXT iteration at H)
        const int next = tile + (int)gridDim.x;
        const bool has_next = next < NT;
        const int n2 = next + (int)gridDim.x;
        const int tl2 = (n2 < NT) ? n2 : tile;
        const float* np2 = efeat + ((size_t)tl2 * 32 + se) * 128 + sd;
        f32x4 eAn = *(const f32x4*)np2;
        f32x4 eBn = *(const f32x4*)(np2 + 4);
        int4 pk2 = pack[(size_t)tl2 * 32 + sub * 16 + el];

        // C) barrier: order LDS double-buffer only — do NOT drain vmcnt
        asm volatile("s_waitcnt lgkmcnt(0)" ::: "memory");
        __builtin_amdgcn_s_barrier();
        __builtin_amdgcn_sched_barrier(0);

        // D) MFMA phase from LDS (lgkmcnt only): 8 fp16 MFMAs on this wave's subtile
        __builtin_amdgcn_s_setprio(1);
        f32x4 acc0 = {}, acc1 = {};
#pragma unroll
        for (int kc = 0; kc < 4; ++kc) {
            const int kb = kc * 32 + g * 8;
            f16x8 be = *(const f16x8*)&lds_e[buf][sub * 16 + el][kb];
            acc0 = __builtin_amdgcn_mfma_f32_16x16x32_f16(wf[0][kc], be, acc0, 0, 0, 0);
            acc1 = __builtin_amdgcn_mfma_f32_16x16x32_f16(wf[1][kc], be, acc1, 0, 0, 0);
        }
        __builtin_amdgcn_s_setprio(0);

        // E) combine: lane covers dims dbase..dbase+8 (acc0 = +0..4, acc1 = +4..8)
        float part = 0.f;
#pragma unroll
        for (int j = 0; j < 4; ++j) {
            part += (float)q16[j]     * (float)k16[j]     * acc0[j];
            part += (float)q16[4 + j] * (float)k16[4 + j] * acc1[j];
        }
        part += __shfl_xor(part, 16, 64);
        part += __shfl_xor(part, 32, 64);
        float sc = part * 0.17677669529663687f;     // 1/sqrt(32)
        sc = fminf(5.0f, fmaxf(-5.0f, sc));
        const float a = __expf(sc);

        const int edge = tile * 32 + sub * 16 + el;
        if (g == 0) {
            attn_out[(size_t)hw * EN + edge] = a;          // coalesced 64B per wave
            attn_csr[(size_t)pk.z * 4 + hw] = a;           // scattered 4B
        }

        if (!has_next) break;

        // H) write tile i+1 into LDS[buf^1] from eA/eB (loaded a FULL iteration ago)
        {
            f16x8 h8;
#pragma unroll
            for (int j = 0; j < 4; ++j) {
                h8[j] = (_Float16)eA[j];
                h8[4 + j] = (_Float16)eB[j];
            }
            *(f16x8*)&lds_e[buf ^ 1][se][sd] = h8;
        }

        // rotate pipeline state
        tile = next;
        pk = pk1;  pk1 = pk2;
        eA = eAn;  eB = eBn;
        buf ^= 1;
    }
}

// ---------------- K2b: per-node gather-reduce + W_fc matvec + residual + LN ----------
// 512 threads = 32 nodes/block, NATURAL node order (R19's degree-sorted indirection
// regressed 55%: CSR/row locality beats intra-block balance).
__global__ __launch_bounds__(512) void node_kernel(
    const int* __restrict__ base, const int* __restrict__ tgt_csr,
    const float* __restrict__ attn_csr, const _Float16* __restrict__ Vh,
    const short* __restrict__ Wfcb, const float* __restrict__ inQ,
    const float* __restrict__ gamma, const float* __restrict__ beta,
    float* __restrict__ y)
{
    __shared__ short wlds[128 * 136];   // padded: stride 136 bf16
    __shared__ float alds[32 * 132];    // padded: stride 132 f32

    const int t = threadIdx.x;
    // stage W_fc: thread handles row r=t>>2, cols (t&3)*32..+31
    {
        const int r = t >> 2, colb = (t & 3) * 32;
#pragma unroll
        for (int c = 0; c < 4; ++c) {
            bf16x8 w = *(const bf16x8*)(Wfcb + r * 128 + colb + c * 8);
            *(bf16x8*)(&wlds[r * 136 + colb + c * 8]) = w;
        }
    }

    const int n_l = t >> 4;             // 0..31
    const int el  = t & 15;
    const int node = blockIdx.x * 32 + n_l;

    int b0 = 0, b1 = 0;
    if (node < NN) { b0 = base[node]; b1 = base[node + 1]; }
    float acc[8] = {};
    float csum = 0.f;
    const int h = el >> 2;

    int p = b0;
    for (; p + 8 <= b1; p += 8) {      // unroll x8 for memory-level parallelism
        int   tg[8];
        float aa[8];
        f16x8 vv[8];
#pragma unroll
        for (int u = 0; u < 8; ++u) tg[u] = tgt_csr[p + u];
#pragma unroll
        for (int u = 0; u < 8; ++u) aa[u] = attn_csr[(size_t)(p + u) * 4 + h];
#pragma unroll
        for (int u = 0; u < 8; ++u) vv[u] = *(const f16x8*)(Vh + (size_t)tg[u] * 128 + el * 8);
#pragma unroll
        for (int u = 0; u < 8; ++u) {
            csum += aa[u];
#pragma unroll
            for (int j = 0; j < 8; ++j) acc[j] += aa[u] * (float)vv[u][j];
        }
    }
    for (; p < b1; ++p) {
        const int tg = tgt_csr[p];
        const float a = attn_csr[(size_t)p * 4 + h];
        f16x8 v = *(const f16x8*)(Vh + (size_t)tg * 128 + el * 8);
        csum += a;
#pragma unroll
        for (int j = 0; j < 8; ++j) acc[j] += a * (float)v[j];
    }

    const float invc = 1.0f / (csum + 1e-8f);
#pragma unroll
    for (int j = 0; j < 8; ++j) alds[n_l * 132 + el * 8 + j] = acc[j] * invc;
    __syncthreads();

    float fc[8] = {};
#pragma unroll 4
    for (int k0 = 0; k0 < 128; k0 += 8) {
        float a8[8];
#pragma unroll
        for (int j = 0; j < 8; ++j) a8[j] = alds[n_l * 132 + k0 + j];
#pragma unroll
        for (int i = 0; i < 8; ++i) {
            const int d = el + 16 * i;
            bf16x8 w = *(const bf16x8*)(&wlds[d * 136 + k0]);
#pragma unroll
            for (int j = 0; j < 8; ++j) fc[i] += a8[j] * bf2f(w[j]);
        }
    }

    if (node < NN) {
        float x[8];
        float s = 0.f, s2 = 0.f;
#pragma unroll
        for (int i = 0; i < 8; ++i) {
            const int d = el + 16 * i;
            x[i] = fc[i] + inQ[(size_t)node * 128 + d];
            s += x[i]; s2 += x[i] * x[i];
        }
        s  += __shfl_xor(s, 1, 64);  s2 += __shfl_xor(s2, 1, 64);
        s  += __shfl_xor(s, 2, 64);  s2 += __shfl_xor(s2, 2, 64);
        s  += __shfl_xor(s, 4, 64);  s2 += __shfl_xor(s2, 4, 64);
        s  += __shfl_xor(s, 8, 64);  s2 += __shfl_xor(s2, 8, 64);
        const float mu = s * (1.0f / 128.0f);
        const float var = s2 * (1.0f / 128.0f) - mu * mu;
        const float rstd = rsqrtf(var + 1e-5f);
#pragma unroll
        for (int i = 0; i < 8; ++i) {
            const int d = el + 16 * i;
            y[(size_t)node * 128 + d] = (x[i] - mu) * rstd * gamma[d] + beta[d];
        }
    }
}

// ---------------- launcher ----------------
extern "C" void kernel_launch(void* const* d_in, const int* in_sizes, int n_in,
                              void* d_out, int out_size, void* d_ws, size_t ws_size,
                              hipStream_t stream) {
    const int*   eidx  = (const int*)d_in[0];
    const float* efeat = (const float*)d_in[1];
    const float* inQ   = (const float*)d_in[2];
    const float* inK   = (const float*)d_in[3];
    const float* inV   = (const float*)d_in[4];
    const float* WQ    = (const float*)d_in[5];
    const float* WK    = (const float*)d_in[6];
    const float* WV    = (const float*)d_in[7];
    const float* WE    = (const float*)d_in[8];
    const float* Wfc   = (const float*)d_in[9];
    const float* gamma = (const float*)d_in[10];
    const float* beta  = (const float*)d_in[11];

    float* y = (float*)d_out;
    float* attn_out = y + (size_t)NN * 128;   // 3,200,000

    // ws layout (bytes):
    //   Qh fp16:               6,400,000 @ 0
    //   Kh fp16:               6,400,000 @ 6,400,000
    //   Vh fp16:               6,400,000 @ 12,800,000
    //   Wf fp16 (4x16384):       131,072 @ 19,200,000   (WQ,WK,WV,WE)
    //   Wfcb bf16 (16384):        32,768 @ 19,331,072
    //   attn_csr f32:          6,400,000 @ 19,363,840
    //   tgt_csr int:           1,600,000 @ 25,763,840
    //   pack int4:             6,400,000 @ 27,363,840
    //   deg int (25088):         100,352 @ 33,763,840   } zeroed
    //   cnt int (25088):         100,352 @ 33,864,192   } zeroed
    //   base_local (25088):      100,352 @ 33,964,544
    //   base_abs (25088):        100,352 @ 34,064,896
    //   bsum int (128):              512 @ 34,165,248
    //   boff int (128):              512 @ 34,165,760  -> total 34,166,272
    char* ws = (char*)d_ws;
    _Float16* Qh   = (_Float16*)ws;
    _Float16* Kh   = (_Float16*)(ws + 6400000);
    _Float16* Vh   = (_Float16*)(ws + 12800000);
    _Float16* Wf   = (_Float16*)(ws + 19200000);
    short* Wfcb    = (short*)(ws + 19331072);
    float* attn_csr= (float*)(ws + 19363840);
    int*   tgt_csr = (int*)  (ws + 25763840);
    int4*  pack    = (int4*) (ws + 27363840);
    int*   deg     = (int*)  (ws + 33763840);
    int*   cnt     = (int*)  (ws + 33864192);
    int*   base_l  = (int*)  (ws + 33964544);
    int*   base_a  = (int*)  (ws + 34064896);
    int*   bsum    = (int*)  (ws + 34165248);
    int*   boff    = (int*)  (ws + 34165760);

    hipMemsetAsync(deg, 0, 200704, stream);   // deg + cnt

    convert_hist_kernel<<<320 + (EN + 255) / 256, 256, 0, stream>>>(
        WQ, WK, WV, WE, Wfc, Wf, Wfcb, eidx, deg);
    scan_a_kernel<<<98, 256, 0, stream>>>(deg, base_l, bsum);
    scan_b_kernel<<<1, 128, 0, stream>>>(bsum, boff);
    scatter2_kernel<<<(EN + 255) / 256, 256, 0, stream>>>(eidx, base_l, boff, cnt,
                                                          pack, tgt_csr, base_a);

    dim3 pg(391, 3);
    proj_all_kernel<<<pg, 256, 0, stream>>>(inQ, inK, inV, Wf, Qh, Kh, Vh);

    edge_score_kernel<<<768, 512, 0, stream>>>(pack, efeat, Qh, Kh, Wf + 3 * 16384,
                                               attn_out, attn_csr);

    node_kernel<<<(NN + 31) / 32, 512, 0, stream>>>(base_a, tgt_csr, attn_csr, Vh,
                                                    Wfcb, inQ, gamma, beta, y);
}